// Round 5
// baseline (92.551 us; speedup 1.0000x reference)
//
#include <hip/hip_runtime.h>
#include <math.h>

#define HW_N   30000
#define NV4    7500
#define W_IMG  200
#define H_IMG  150
#define NPERS  5
#define CAP    1024
#define BASE_BITS 0x40400000u      // float bits of 3.0f; masked depth in (3,12) => 24-bit key
#define VCAP   4096                // per-(batch,person) capture cap (mean 3750, +6 sigma)

#ifndef M_PI
#define M_PI 3.14159265358979323846
#endif

__device__ __forceinline__ unsigned wave_incl_scan_u32(unsigned v, int lane) {
    #pragma unroll
    for (int d = 1; d < 64; d <<= 1) {
        unsigned t = __shfl_up(v, d, 64);
        if (lane >= d) v += t;
    }
    return v;
}

__device__ __forceinline__ int person_of(float f) {
    float r = rintf(f);
    int p = (int)r;
    return (p >= 1 && p <= NPERS && (float)p == r) ? p : 0;
}

// 256-bin selection: all 64 lanes of one wave, h in LDS, plain u32 counts.
__device__ __forceinline__ void sel256(const unsigned* h, unsigned k, int lane,
                                       unsigned& bucket, unsigned& krem) {
    unsigned run = 0; bucket = 0; krem = 0;
    bool found = false;
    #pragma unroll
    for (int c = 0; c < 4; ++c) {
        if (found) continue;
        unsigned hv = h[c * 64 + lane];
        unsigned inc = wave_incl_scan_u32(hv, lane);
        unsigned tot = __shfl(inc, 63, 64);
        if (run + tot > k) {
            unsigned long long m = __ballot((run + inc) > k);
            int l = (int)__builtin_ctzll(m);
            bucket = (unsigned)(c * 64 + l);
            krem = k - (run + __shfl(inc, l, 64) - __shfl(hv, l, 64));
            found = true;
        } else run += tot;
    }
}

// ================= K1: capture 24-bit keys per (batch,person) =================
__global__ __launch_bounds__(256)
void k1_capture(const float* __restrict__ in, unsigned* __restrict__ vals,
                unsigned* __restrict__ cnt) {
    const int bid = blockIdx.x;
    const int b = bid >> 2, s = bid & 3;
    const int tid = (int)threadIdx.x, lane = tid & 63;
    const float* __restrict__ depth = in + (size_t)b * 3u * HW_N;
    const float4* __restrict__ d4p = (const float4*)depth;
    const float4* __restrict__ i4p = (const float4*)(depth + HW_N);
    const int f40 = s * (NV4 / 4), f41 = f40 + (NV4 / 4);

    for (int base4 = f40; base4 < f41; base4 += 256) {
        int i = base4 + tid;
        bool valid = i < f41;
        float4 dd, ff;
        if (valid) { dd = d4p[i]; ff = i4p[i]; }
        int pf[4] = {0, 0, 0, 0};
        unsigned kk[4] = {0, 0, 0, 0};
        if (valid) {
            float de[4] = {dd.x, dd.y, dd.z, dd.w};
            float fe[4] = {ff.x, ff.y, ff.z, ff.w};
            #pragma unroll
            for (int e = 0; e < 4; ++e) {
                float d = de[e];
                int p = person_of(fe[e]);
                if (p && d > 3.0f) { pf[e] = p; kk[e] = __float_as_uint(d) - BASE_BITS; }
            }
        }
        #pragma unroll
        for (int pp = 1; pp <= NPERS; ++pp) {
            unsigned m0 = (pf[0] == pp), m1 = (pf[1] == pp);
            unsigned m2 = (pf[2] == pp), m3 = (pf[3] == pp);
            unsigned c = m0 + m1 + m2 + m3;
            unsigned incl = wave_incl_scan_u32(c, lane);
            unsigned tot = __shfl(incl, 63, 64);
            if (tot == 0u) continue;                     // wave-uniform
            unsigned base = 0u;
            if (lane == 0) base = atomicAdd(&cnt[b * NPERS + pp - 1], tot);
            base = (unsigned)__shfl((int)base, 0, 64);
            unsigned wexc = incl - c;
            unsigned* vp = vals + (size_t)(b * NPERS + pp - 1) * VCAP;
            unsigned o = base + wexc;
            if (m0 && o < VCAP) vp[o] = kk[0];
            o += m0;
            if (m1 && o < VCAP) vp[o] = kk[1];
            o += m1;
            if (m2 && o < VCAP) vp[o] = kk[2];
            o += m2;
            if (m3 && o < VCAP) vp[o] = kk[3];
        }
    }
}

// ================= K2: exact quartiles -> lb/ub per (batch,person) =================
__global__ __launch_bounds__(256)
void k2_select(const unsigned* __restrict__ vals, const unsigned* __restrict__ cnt,
               float* __restrict__ bounds) {
    const int bp = blockIdx.x;
    const int tid = (int)threadIdx.x, lane = tid & 63, wv = tid >> 6;

    __shared__ unsigned s_v[VCAP];      // 16 KB compact keys
    __shared__ unsigned s_h1[256];
    __shared__ unsigned s_h2[4 * 256];
    __shared__ unsigned s_pref[4];
    __shared__ unsigned s_krem[4];
    __shared__ float    s_val[4];

    unsigned n = cnt[bp];
    if (n == 0u) {
        if (tid == 0) { bounds[bp * 2] = INFINITY; bounds[bp * 2 + 1] = -INFINITY; }
        return;
    }
    unsigned nn = n > VCAP ? VCAP : n;
    s_h1[tid] = 0u;
    #pragma unroll
    for (int j = 0; j < 4; ++j) s_h2[j * 256 + tid] = 0u;
    __syncthreads();

    const unsigned* vsrc = vals + (size_t)bp * VCAP;
    for (int i = tid; i < (int)nn; i += 256) {
        unsigned v = vsrc[i];
        s_v[i] = v;
        atomicAdd(&s_h1[v >> 16], 1u);
    }
    __syncthreads();

    // stage 1: wave wv handles order-stat wv
    {
        float nf = (float)n;
        float m1 = fmaxf(nf - 1.0f, 0.0f);
        float pos = ((wv >> 1) ? 0.75f : 0.25f) * m1;   // exact in f32
        unsigned k = (unsigned)((wv & 1) ? (int)ceilf(pos) : (int)floorf(pos));
        unsigned bucket, krem;
        sel256(s_h1, k, lane, bucket, krem);
        if (lane == 0) { s_pref[wv] = bucket; s_krem[wv] = krem; }
    }
    __syncthreads();

    // stage 2: bits[15:8]
    {
        unsigned p0 = s_pref[0], p1 = s_pref[1], p2 = s_pref[2], p3 = s_pref[3];
        for (int i = tid; i < (int)nn; i += 256) {
            unsigned v = s_v[i];
            unsigned t8 = v >> 16, b8 = (v >> 8) & 255u;
            if (t8 == p0) atomicAdd(&s_h2[b8], 1u);
            if (t8 == p1) atomicAdd(&s_h2[256 + b8], 1u);
            if (t8 == p2) atomicAdd(&s_h2[512 + b8], 1u);
            if (t8 == p3) atomicAdd(&s_h2[768 + b8], 1u);
        }
    }
    __syncthreads();
    {
        unsigned bucket, krem;
        sel256(&s_h2[wv * 256], s_krem[wv], lane, bucket, krem);
        if (lane == 0) { s_pref[wv] = (s_pref[wv] << 8) | bucket; s_krem[wv] = krem; }
    }
    __syncthreads();
    #pragma unroll
    for (int j = 0; j < 4; ++j) s_h2[j * 256 + tid] = 0u;
    __syncthreads();

    // stage 3: bits[7:0]
    {
        unsigned p0 = s_pref[0], p1 = s_pref[1], p2 = s_pref[2], p3 = s_pref[3];
        for (int i = tid; i < (int)nn; i += 256) {
            unsigned v = s_v[i];
            unsigned t16 = v >> 8, b8 = v & 255u;
            if (t16 == p0) atomicAdd(&s_h2[b8], 1u);
            if (t16 == p1) atomicAdd(&s_h2[256 + b8], 1u);
            if (t16 == p2) atomicAdd(&s_h2[512 + b8], 1u);
            if (t16 == p3) atomicAdd(&s_h2[768 + b8], 1u);
        }
    }
    __syncthreads();
    {
        unsigned bucket, krem;
        sel256(&s_h2[wv * 256], s_krem[wv], lane, bucket, krem);
        if (lane == 0) s_val[wv] = __uint_as_float(BASE_BITS + ((s_pref[wv] << 8) | bucket));
    }
    __syncthreads();

    if (tid == 0) {
        // mirror reference f32 arithmetic with non-fused IEEE ops (verified absmax 0.0)
        float nf = (float)n;
        float m1 = fmaxf(nf - 1.0f, 0.0f);
        float pos1 = 0.25f * m1, pos3 = 0.75f * m1;
        float fr1 = pos1 - floorf(pos1);
        float fr3 = pos3 - floorf(pos3);
        float q1 = __fadd_rn(__fmul_rn(s_val[0], __fsub_rn(1.0f, fr1)),
                             __fmul_rn(s_val[1], fr1));
        float q3 = __fadd_rn(__fmul_rn(s_val[2], __fsub_rn(1.0f, fr3)),
                             __fmul_rn(s_val[3], fr3));
        float iqr = __fsub_rn(q3, q1);
        float t15 = __fmul_rn(1.5f, iqr);
        bounds[bp * 2]     = __fsub_rn(q1, t15);
        bounds[bp * 2 + 1] = __fadd_rn(q3, t15);
    }
}

// ================= K3: per-(batch,person) stable compaction + fill =================
__global__ __launch_bounds__(256)
void k3_output(const float* __restrict__ in, const float* __restrict__ bounds,
               float* __restrict__ out) {
    const int bp = blockIdx.x;
    const int b = bp / NPERS, p = bp % NPERS;          // p 0-based
    const int tid = (int)threadIdx.x, lane = tid & 63, wv = tid >> 6;
    const int ptgt = p + 1;

    __shared__ float s_xc[W_IMG], s_yc[H_IMG];
    __shared__ unsigned s_wcnt[4], s_woff[4];
    __shared__ unsigned s_gbase;

    if (tid < W_IMG) {
        const double fx = 200.0 / (2.0 * tan((81.0 * (M_PI / 180.0)) / 2.0));
        s_xc[tid] = (float)(((double)tid - 100.0) / fx);
    }
    if (tid < H_IMG) {
        const double fy = 150.0 / (2.0 * tan((59.0 * (M_PI / 180.0)) / 2.0));
        s_yc[tid] = (float)(((double)tid - 75.0) / fy);
    }
    if (tid == 0) s_gbase = 0u;

    const float lb = bounds[bp * 2], ub = bounds[bp * 2 + 1];
    const float* __restrict__ depth = in + (size_t)b * 3u * HW_N;
    const float4* __restrict__ d4p = (const float4*)depth;
    const float4* __restrict__ i4p = (const float4*)(depth + HW_N);
    float* r0 = out + (size_t)b * 3u * (NPERS * (CAP + 1)) + (size_t)p * (CAP + 1);
    const int cstr = NPERS * (CAP + 1);                // 5125
    __syncthreads();

    for (int base4 = 0; base4 < NV4; base4 += 256) {
        int i = base4 + tid;
        bool valid = i < NV4;
        float4 dd, ff;
        if (valid) { dd = d4p[i]; ff = i4p[i]; }
        unsigned m[4] = {0, 0, 0, 0};
        float dv[4] = {0.f, 0.f, 0.f, 0.f};
        if (valid) {
            float de[4] = {dd.x, dd.y, dd.z, dd.w};
            float fe[4] = {ff.x, ff.y, ff.z, ff.w};
            #pragma unroll
            for (int e = 0; e < 4; ++e) {
                float d = de[e];
                dv[e] = d;
                if (person_of(fe[e]) == ptgt && d > 3.0f && d >= lb && d <= ub) m[e] = 1u;
            }
        }
        unsigned c = m[0] + m[1] + m[2] + m[3];
        unsigned incl = wave_incl_scan_u32(c, lane);
        if (lane == 63) s_wcnt[wv] = incl;
        unsigned wexc = incl - c;
        __syncthreads();                               // B1
        if (tid == 0) {
            unsigned o = s_gbase;
            #pragma unroll
            for (int w = 0; w < 4; ++w) { s_woff[w] = o; o += s_wcnt[w]; }
            s_gbase = o;
        }
        __syncthreads();                               // B2
        if (c) {
            unsigned o = s_woff[wv] + wexc;
            #pragma unroll
            for (int e = 0; e < 4; ++e) {
                if (m[e]) {
                    if (o < CAP) {
                        int idx = i * 4 + e;
                        int y = idx / W_IMG, x = idx - y * W_IMG;
                        float d = dv[e];
                        r0[o]            = __fmul_rn(s_xc[x], d);
                        r0[cstr + o]     = __fmul_rn(s_yc[y], d);
                        r0[2 * cstr + o] = d;
                    }
                    ++o;
                }
            }
        }
        if (s_gbase >= (unsigned)CAP) break;           // uniform (read between B2 and next B1)
    }
    __syncthreads();
    unsigned cntv = s_gbase;
    unsigned cl = cntv > (unsigned)CAP ? (unsigned)CAP : cntv;
    for (int j = (int)cl + tid; j < CAP; j += 256) {
        r0[j] = 0.0f; r0[cstr + j] = 0.0f; r0[2 * cstr + j] = 0.0f;
    }
    if (tid == 0) {
        r0[CAP] = (cntv > 0u) ? 1.0f : 0.0f;
        r0[cstr + CAP] = 0.0f;
        r0[2 * cstr + CAP] = 0.0f;
    }
}

// ================= Fallback: verified round-4 single kernel =================
#define NTHR 1024
#define NWAVE 16
#define CAPS 384
#define NREG (NWAVE * NPERS)

__device__ __forceinline__ void find_bucket_fb(const unsigned* h, int nchunks, unsigned k,
                                               int lane, unsigned& bucket, unsigned& cl) {
    unsigned run = 0;
    bucket = 0; cl = 0;
    bool found = false;
    for (int c = 0; c < nchunks; ++c) {
        if (found) break;
        unsigned hv = h[c * 64 + lane] & 0xFFFFu;
        unsigned inc = wave_incl_scan_u32(hv, lane);
        unsigned tot = __shfl(inc, 63, 64);
        if (run + tot > k) {
            unsigned long long m = __ballot((run + inc) > k);
            int l = (int)__builtin_ctzll(m);
            bucket = (unsigned)(c * 64 + l);
            cl = run + __shfl(inc, l, 64) - __shfl(hv, l, 64);
            found = true;
        }
        run += tot;
    }
}

__global__ __launch_bounds__(NTHR)
void fb_kernel(const float* __restrict__ in, float* __restrict__ out) {
    const int b = blockIdx.x;
    const int tid = (int)threadIdx.x;
    const int lane = tid & 63;
    const int wv = tid >> 6;
    const float* __restrict__ depth = in + (size_t)b * 3u * HW_N;
    const float* __restrict__ indc = depth + HW_N;
    const float4* __restrict__ d4p = (const float4*)depth;
    const float4* __restrict__ i4p = (const float4*)indc;

    __shared__ unsigned s_vals[NREG * CAPS];
    __shared__ unsigned s_cur[NREG];
    __shared__ unsigned s_h1[NPERS * 256];
    __shared__ unsigned s_h2[20 * 256];
    __shared__ __align__(16) unsigned s_pref[24];
    __shared__ int      s_krem[20];
    __shared__ float    s_val[20];
    __shared__ unsigned s_n[NPERS];
    __shared__ float    s_lb[NPERS], s_ub[NPERS];
    __shared__ unsigned s_cnt[NWAVE][NPERS];
    __shared__ unsigned s_woff[NWAVE][NPERS];
    __shared__ unsigned s_tot[NPERS];
    __shared__ unsigned s_base[NPERS];
    __shared__ float    s_xc[W_IMG];
    __shared__ float    s_yc[H_IMG];

    for (int i = tid; i < NPERS * 256; i += NTHR) s_h1[i] = 0u;
    for (int i = tid; i < 20 * 256; i += NTHR) s_h2[i] = 0u;
    if (tid < NREG) s_cur[tid] = 0u;
    if (tid < NPERS) { s_base[tid] = 0u; s_tot[tid] = 0u; }
    if (tid < W_IMG) {
        const double fx = 200.0 / (2.0 * tan((81.0 * (M_PI / 180.0)) / 2.0));
        s_xc[tid] = (float)(((double)tid - 100.0) / fx);
    }
    {
        int ty = tid - 256;
        if (ty >= 0 && ty < H_IMG) {
            const double fy = 150.0 / (2.0 * tan((59.0 * (M_PI / 180.0)) / 2.0));
            s_yc[ty] = (float)(((double)ty - 75.0) / fy);
        }
    }
    __syncthreads();

    {
        int i = tid;
        float4 dd = d4p[i], ff = i4p[i];
        while (i < NV4) {
            int inx = i + NTHR;
            float4 dd2, ff2;
            if (inx < NV4) { dd2 = d4p[inx]; ff2 = i4p[inx]; }
            float de[4] = {dd.x, dd.y, dd.z, dd.w};
            float fe[4] = {ff.x, ff.y, ff.z, ff.w};
            #pragma unroll
            for (int e = 0; e < 4; ++e) {
                float d = de[e];
                int p = person_of(fe[e]);
                if (p && d > 3.0f) {
                    unsigned k24 = __float_as_uint(d) - BASE_BITS;
                    atomicAdd(&s_h1[(p - 1) * 256 + (k24 >> 16)], 1u);
                    int reg = wv * NPERS + (p - 1);
                    unsigned off = atomicAdd(&s_cur[reg], 1u);
                    if (off < CAPS) s_vals[reg * CAPS + off] = k24;
                }
            }
            dd = dd2; ff = ff2;
            i = inx;
        }
    }
    __syncthreads();

    if (tid < NPERS) {
        unsigned n = 0;
        for (int sh = 0; sh < NWAVE; ++sh) n += s_cur[sh * NPERS + tid];
        s_n[tid] = n;
    }
    __syncthreads();

    for (int q = wv; q < 20; q += NWAVE) {
        int p = q >> 2, s = q & 3;
        unsigned n = s_n[p];
        if (n == 0u) { if (lane == 0) s_pref[q] = 0xFFFFFFFFu; continue; }
        float nf = (float)n;
        float m1 = fmaxf(nf - 1.0f, 0.0f);
        float pos = ((s >> 1) ? 0.75f : 0.25f) * m1;
        unsigned k = (unsigned)((s & 1) ? (int)ceilf(pos) : (int)floorf(pos));
        unsigned bucket, cl;
        find_bucket_fb(&s_h1[p * 256], 4, k, lane, bucket, cl);
        if (lane == 0) { s_pref[q] = bucket; s_krem[q] = (int)(k - cl); }
    }
    __syncthreads();

    for (int t = tid; t < NREG * CAPS; t += NTHR) {
        int reg = t / CAPS;
        int ii = t - reg * CAPS;
        unsigned cnt = s_cur[reg]; if (cnt > CAPS) cnt = CAPS;
        if ((unsigned)ii < cnt) {
            unsigned k24 = s_vals[t];
            int p = reg % NPERS;
            unsigned t8 = k24 >> 16;
            uint4 pr = *(const uint4*)&s_pref[p * 4];
            unsigned b8 = (k24 >> 8) & 255u;
            if (t8 == pr.x) atomicAdd(&s_h2[(p * 4 + 0) * 256 + b8], 1u);
            if (t8 == pr.y) atomicAdd(&s_h2[(p * 4 + 1) * 256 + b8], 1u);
            if (t8 == pr.z) atomicAdd(&s_h2[(p * 4 + 2) * 256 + b8], 1u);
            if (t8 == pr.w) atomicAdd(&s_h2[(p * 4 + 3) * 256 + b8], 1u);
        }
    }
    __syncthreads();

    for (int q = wv; q < 20; q += NWAVE) {
        int p = q >> 2;
        if (s_n[p] == 0u) continue;
        unsigned bucket, cl;
        find_bucket_fb(&s_h2[q * 256], 4, (unsigned)s_krem[q], lane, bucket, cl);
        if (lane == 0) { s_pref[q] = (s_pref[q] << 8) | bucket; s_krem[q] -= (int)cl; }
    }
    __syncthreads();
    for (int i = tid; i < 20 * 256; i += NTHR) s_h2[i] = 0u;
    __syncthreads();

    for (int t = tid; t < NREG * CAPS; t += NTHR) {
        int reg = t / CAPS;
        int ii = t - reg * CAPS;
        unsigned cnt = s_cur[reg]; if (cnt > CAPS) cnt = CAPS;
        if ((unsigned)ii < cnt) {
            unsigned k24 = s_vals[t];
            int p = reg % NPERS;
            unsigned t16 = k24 >> 8;
            uint4 pr = *(const uint4*)&s_pref[p * 4];
            unsigned b8 = k24 & 255u;
            if (t16 == pr.x) atomicAdd(&s_h2[(p * 4 + 0) * 256 + b8], 1u);
            if (t16 == pr.y) atomicAdd(&s_h2[(p * 4 + 1) * 256 + b8], 1u);
            if (t16 == pr.z) atomicAdd(&s_h2[(p * 4 + 2) * 256 + b8], 1u);
            if (t16 == pr.w) atomicAdd(&s_h2[(p * 4 + 3) * 256 + b8], 1u);
        }
    }
    __syncthreads();

    for (int q = wv; q < 20; q += NWAVE) {
        int p = q >> 2;
        if (s_n[p] == 0u) continue;
        unsigned bucket, cl;
        find_bucket_fb(&s_h2[q * 256], 4, (unsigned)s_krem[q], lane, bucket, cl);
        if (lane == 0) s_val[q] = __uint_as_float(BASE_BITS + ((s_pref[q] << 8) | bucket));
    }
    __syncthreads();

    if (tid < NPERS) {
        if (s_n[tid] == 0u) {
            s_lb[tid] = INFINITY; s_ub[tid] = -INFINITY;
        } else {
            float nf = (float)s_n[tid];
            float m1 = fmaxf(nf - 1.0f, 0.0f);
            float pos1 = 0.25f * m1, pos3 = 0.75f * m1;
            float fr1 = pos1 - floorf(pos1);
            float fr3 = pos3 - floorf(pos3);
            float q1 = __fadd_rn(__fmul_rn(s_val[tid * 4 + 0], __fsub_rn(1.0f, fr1)),
                                 __fmul_rn(s_val[tid * 4 + 1], fr1));
            float q3 = __fadd_rn(__fmul_rn(s_val[tid * 4 + 2], __fsub_rn(1.0f, fr3)),
                                 __fmul_rn(s_val[tid * 4 + 3], fr3));
            float iqr = __fsub_rn(q3, q1);
            float t15 = __fmul_rn(1.5f, iqr);
            s_lb[tid] = __fsub_rn(q1, t15);
            s_ub[tid] = __fadd_rn(q3, t15);
        }
    }
    __syncthreads();

    float* outb = out + (size_t)b * 3u * (NPERS * (CAP + 1));
    const int cstr = NPERS * (CAP + 1);

    for (int t0 = 0; t0 < NV4; t0 += NTHR) {
        int i = t0 + tid;
        int pf[4] = {0, 0, 0, 0};
        float dv[4] = {0.f, 0.f, 0.f, 0.f};
        if (i < NV4) {
            float4 dd = d4p[i];
            float4 ff = i4p[i];
            float de[4] = {dd.x, dd.y, dd.z, dd.w};
            float fe[4] = {ff.x, ff.y, ff.z, ff.w};
            #pragma unroll
            for (int e = 0; e < 4; ++e) {
                float d = de[e];
                int p = person_of(fe[e]);
                dv[e] = d;
                if (p && d > 3.0f && d >= s_lb[p - 1] && d <= s_ub[p - 1]) pf[e] = p;
            }
        }
        unsigned wexc[NPERS];
        #pragma unroll
        for (int pp = 0; pp < NPERS; ++pp) {
            unsigned c = (unsigned)((pf[0] == pp + 1) + (pf[1] == pp + 1) +
                                    (pf[2] == pp + 1) + (pf[3] == pp + 1));
            unsigned incl = wave_incl_scan_u32(c, lane);
            if (lane == 63) s_cnt[wv][pp] = incl;
            wexc[pp] = incl - c;
        }
        __syncthreads();
        if (tid < 16 * NPERS) {
            int p = tid >> 4, w = tid & 15;
            unsigned o = s_base[p];
            for (int w2 = 0; w2 < w; ++w2) o += s_cnt[w2][p];
            s_woff[w][p] = o;
            if (w == 15) s_tot[p] = o + s_cnt[15][p];
        }
        __syncthreads();
        #pragma unroll
        for (int pp = 0; pp < NPERS; ++pp) {
            unsigned m0 = (pf[0] == pp + 1), m1 = (pf[1] == pp + 1);
            unsigned m2 = (pf[2] == pp + 1), m3 = (pf[3] == pp + 1);
            if ((m0 | m1 | m2 | m3) != 0u) {
                unsigned basep = s_woff[wv][pp] + wexc[pp];
                #define WRITEPT(e, mm, pre)                                                \
                    if (mm) { unsigned off = basep + (pre);                                \
                        if (off < CAP) {                                                   \
                            int idx = i * 4 + e; int y = idx / W_IMG; int x = idx - y * W_IMG; \
                            size_t o = (size_t)pp * (CAP + 1) + off; float d = dv[e];      \
                            outb[o] = __fmul_rn(s_xc[x], d);                               \
                            outb[cstr + o] = __fmul_rn(s_yc[y], d);                        \
                            outb[2 * cstr + o] = d; } }
                WRITEPT(0, m0, 0u)
                WRITEPT(1, m1, m0)
                WRITEPT(2, m2, m0 + m1)
                WRITEPT(3, m3, m0 + m1 + m2)
                #undef WRITEPT
            }
        }
        if (tid < NPERS) s_base[tid] = s_tot[tid];
        bool done = true;
        #pragma unroll
        for (int pp = 0; pp < NPERS; ++pp) done = done && (s_tot[pp] >= (unsigned)CAP);
        if (done) break;
    }
    __syncthreads();

    for (int t = tid; t < NPERS * (CAP + 1); t += NTHR) {
        int p = t / (CAP + 1);
        int j = t - p * (CAP + 1);
        unsigned cnt = s_tot[p];
        size_t o = (size_t)p * (CAP + 1) + j;
        if (j == CAP) {
            outb[o] = (cnt > 0u) ? 1.0f : 0.0f;
            outb[cstr + o] = 0.0f;
            outb[2 * cstr + o] = 0.0f;
        } else if ((unsigned)j >= cnt) {
            outb[o] = 0.0f;
            outb[cstr + o] = 0.0f;
            outb[2 * cstr + o] = 0.0f;
        }
    }
}

extern "C" void kernel_launch(void* const* d_in, const int* in_sizes, int n_in,
                              void* d_out, int out_size, void* d_ws, size_t ws_size,
                              hipStream_t stream) {
    const float* in = (const float*)d_in[0];
    float* out = (float*)d_out;
    int B = in_sizes[0] / (3 * HW_N);   // 256

    const size_t vals_bytes = (size_t)B * NPERS * VCAP * 4;        // 20.97 MB
    const size_t cnt_off    = vals_bytes;
    const size_t cnt_bytes  = (size_t)B * NPERS * 4;               // 5 KB
    const size_t bnd_off    = cnt_off + cnt_bytes;
    const size_t bnd_bytes  = (size_t)B * NPERS * 2 * 4;           // 10 KB
    const size_t req        = bnd_off + bnd_bytes;

    if (ws_size >= req) {
        unsigned* vals = (unsigned*)d_ws;
        unsigned* cnt  = (unsigned*)((char*)d_ws + cnt_off);
        float* bounds  = (float*)((char*)d_ws + bnd_off);
        hipMemsetAsync(cnt, 0, cnt_bytes, stream);
        hipLaunchKernelGGL(k1_capture, dim3(B * 4), dim3(256), 0, stream, in, vals, cnt);
        hipLaunchKernelGGL(k2_select, dim3(B * NPERS), dim3(256), 0, stream, vals, cnt, bounds);
        hipLaunchKernelGGL(k3_output, dim3(B * NPERS), dim3(256), 0, stream, in, bounds, out);
    } else {
        hipLaunchKernelGGL(fb_kernel, dim3(B), dim3(NTHR), 0, stream, in, out);
    }
}

// Round 6
// 83.222 us; speedup vs baseline: 1.1121x; 1.1121x over previous
//
#include <hip/hip_runtime.h>
#include <math.h>

#define HW_N   30000
#define NV4    7500
#define W_IMG  200
#define H_IMG  150
#define NPERS  5
#define CAP    1024
#define BASE_BITS 0x40400000u      // float bits of 3.0f; masked depth in (3,12) => 24-bit key
#define NSUB   4                   // sub-blocks per batch in K1
#define REG    1152                // per-(b,p,s) region slots (mean 937.5, +7.5 sigma)
#define TOTV   (NSUB * REG)        // 4608 max values per (b,p)

#ifndef M_PI
#define M_PI 3.14159265358979323846
#endif

__device__ __forceinline__ unsigned wave_incl_scan_u32(unsigned v, int lane) {
    #pragma unroll
    for (int d = 1; d < 64; d <<= 1) {
        unsigned t = __shfl_up(v, d, 64);
        if (lane >= d) v += t;
    }
    return v;
}

__device__ __forceinline__ int person_of(float f) {
    float r = rintf(f);
    int p = (int)r;
    return (p >= 1 && p <= NPERS && (float)p == r) ? p : 0;
}

// 256-bin selection: all 64 lanes of one wave, h in LDS, plain u32 counts.
__device__ __forceinline__ void sel256(const unsigned* h, unsigned k, int lane,
                                       unsigned& bucket, unsigned& krem) {
    unsigned run = 0; bucket = 0; krem = 0;
    bool found = false;
    #pragma unroll
    for (int c = 0; c < 4; ++c) {
        if (found) continue;
        unsigned hv = h[c * 64 + lane];
        unsigned inc = wave_incl_scan_u32(hv, lane);
        unsigned tot = __shfl(inc, 63, 64);
        if (run + tot > k) {
            unsigned long long m = __ballot((run + inc) > k);
            int l = (int)__builtin_ctzll(m);
            bucket = (unsigned)(c * 64 + l);
            krem = k - (run + __shfl(inc, l, 64) - __shfl(hv, l, 64));
            found = true;
        } else run += tot;
    }
}

// ========== K1: order-preserving u16-index capture, zero global atomics ==========
__global__ __launch_bounds__(256)
void k1_capture(const float* __restrict__ in, unsigned short* __restrict__ vals16,
                unsigned* __restrict__ cnt4) {
    const int bid = blockIdx.x;
    const int b = bid >> 2, s = bid & 3;
    const int tid = (int)threadIdx.x, lane = tid & 63, wv = tid >> 6;
    const float* __restrict__ depth = in + (size_t)b * 3u * HW_N;
    const float4* __restrict__ d4p = (const float4*)depth;
    const float4* __restrict__ i4p = (const float4*)(depth + HW_N);
    const int f40 = s * (NV4 / NSUB), f41 = f40 + (NV4 / NSUB);   // 1875 float4 each

    __shared__ unsigned s_wcnt[4][NPERS];
    __shared__ unsigned s_woff[4][NPERS];
    __shared__ unsigned s_cur[NPERS];
    if (tid < NPERS) s_cur[tid] = 0u;
    __syncthreads();

    for (int base4 = f40; base4 < f41; base4 += 256) {
        int i = base4 + tid;
        bool valid = i < f41;
        float4 dd, ff;
        if (valid) { dd = d4p[i]; ff = i4p[i]; }
        int pf[4] = {0, 0, 0, 0};
        if (valid) {
            float de[4] = {dd.x, dd.y, dd.z, dd.w};
            float fe[4] = {ff.x, ff.y, ff.z, ff.w};
            #pragma unroll
            for (int e = 0; e < 4; ++e) {
                int p = person_of(fe[e]);
                if (p && de[e] > 3.0f) pf[e] = p;
            }
        }
        // packed per-person counts: persons 1-3 in pk0 (10-bit fields), 4-5 in pk1
        unsigned pk0 = 0u, pk1 = 0u;
        #pragma unroll
        for (int e = 0; e < 4; ++e) {
            int p = pf[e];
            if (p >= 1 && p <= 3) pk0 += 1u << (10 * (p - 1));
            if (p >= 4) pk1 += 1u << (10 * (p - 4));
        }
        unsigned inc0 = wave_incl_scan_u32(pk0, lane);
        unsigned inc1 = wave_incl_scan_u32(pk1, lane);
        if (lane == 63) {
            #pragma unroll
            for (int p = 0; p < 3; ++p) s_wcnt[wv][p] = (inc0 >> (10 * p)) & 1023u;
            #pragma unroll
            for (int p = 3; p < 5; ++p) s_wcnt[wv][p] = (inc1 >> (10 * (p - 3))) & 1023u;
        }
        unsigned exc0 = inc0 - pk0, exc1 = inc1 - pk1;
        __syncthreads();                               // B1
        if (tid < 20) {                                 // all in wave 0: lockstep-safe
            int p = tid % 5, w = tid / 5;
            unsigned o = s_cur[p];
            for (int w2 = 0; w2 < w; ++w2) o += s_wcnt[w2][p];
            s_woff[w][p] = o;
            if (w == 3) s_cur[p] = o + s_wcnt[3][p];
        }
        __syncthreads();                               // B2
        #pragma unroll
        for (int pp = 1; pp <= NPERS; ++pp) {
            unsigned wexc = (pp <= 3) ? ((exc0 >> (10 * (pp - 1))) & 1023u)
                                      : ((exc1 >> (10 * (pp - 4))) & 1023u);
            unsigned o = s_woff[wv][pp - 1] + wexc;
            unsigned short* vp = vals16 + ((size_t)(b * NPERS + pp - 1) * NSUB + s) * REG;
            #pragma unroll
            for (int e = 0; e < 4; ++e) {
                if (pf[e] == pp) {
                    if (o < REG) vp[o] = (unsigned short)(i * 4 + e);
                    ++o;
                }
            }
        }
        __syncthreads();                               // protect s_wcnt reuse
    }
    if (tid < NPERS)
        cnt4[((size_t)(b * NPERS + tid) * NSUB) + s] = s_cur[tid];
}

// ========== K2: per-(b,p) select (exact quartiles) + stable compaction ==========
__global__ __launch_bounds__(256)
void k2_out(const float* __restrict__ in, const unsigned short* __restrict__ vals16,
            const unsigned* __restrict__ cnt4, float* __restrict__ out) {
    const int bp = blockIdx.x;
    const int b = bp / NPERS, p = bp % NPERS;
    const int tid = (int)threadIdx.x, lane = tid & 63, wv = tid >> 6;

    __shared__ unsigned short s_idx[TOTV];    // 9.2 KB
    __shared__ unsigned s_key[TOTV];          // 18.4 KB
    __shared__ unsigned s_h1[256];
    __shared__ unsigned s_h2[4 * 256];
    __shared__ unsigned s_pref[4], s_krem[4];
    __shared__ float    s_val[4];
    __shared__ float    s_lb, s_ub;
    __shared__ float    s_xc[W_IMG], s_yc[H_IMG];
    __shared__ unsigned s_c4[NSUB], s_off[NSUB];
    __shared__ unsigned s_wc[4], s_wo[4];
    __shared__ unsigned s_gbase;

    const float* __restrict__ depth = in + (size_t)b * 3u * HW_N;
    float* r0 = out + (size_t)b * 3u * (NPERS * (CAP + 1)) + (size_t)p * (CAP + 1);
    const int cstr = NPERS * (CAP + 1);       // 5125

    if (tid < NSUB) {
        unsigned c = cnt4[(size_t)bp * NSUB + tid];
        s_c4[tid] = c > REG ? REG : c;
    }
    s_h1[tid] = 0u;
    #pragma unroll
    for (int j = 0; j < 4; ++j) s_h2[j * 256 + tid] = 0u;
    if (tid < W_IMG) {
        const double fx = 200.0 / (2.0 * tan((81.0 * (M_PI / 180.0)) / 2.0));
        s_xc[tid] = (float)(((double)tid - 100.0) / fx);
    }
    if (tid < H_IMG) {
        const double fy = 150.0 / (2.0 * tan((59.0 * (M_PI / 180.0)) / 2.0));
        s_yc[tid] = (float)(((double)tid - 75.0) / fy);
    }
    if (tid == 0) s_gbase = 0u;
    __syncthreads();

    if (tid == 0) {
        unsigned o = 0;
        #pragma unroll
        for (int ss = 0; ss < NSUB; ++ss) { s_off[ss] = o; o += s_c4[ss]; }
    }
    __syncthreads();
    const int n = (int)(s_off[NSUB - 1] + s_c4[NSUB - 1]);

    if (n == 0) {
        for (int j = tid; j < CAP; j += 256) {
            r0[j] = 0.0f; r0[cstr + j] = 0.0f; r0[2 * cstr + j] = 0.0f;
        }
        if (tid == 0) { r0[CAP] = 0.0f; r0[cstr + CAP] = 0.0f; r0[2 * cstr + CAP] = 0.0f; }
        return;
    }

    // load index lists (order-correct: sub-regions concatenated in s order)
    #pragma unroll
    for (int ss = 0; ss < NSUB; ++ss) {
        const unsigned short* vp = vals16 + ((size_t)bp * NSUB + ss) * REG;
        unsigned c = s_c4[ss], o = s_off[ss];
        for (unsigned j = tid; j < c; j += 256) s_idx[o + j] = vp[j];
    }
    __syncthreads();

    // gather depth, build keys + stage-1 histogram (bits[23:16])
    for (int j = tid; j < n; j += 256) {
        float d = depth[s_idx[j]];
        unsigned key = __float_as_uint(d) - BASE_BITS;
        s_key[j] = key;
        atomicAdd(&s_h1[key >> 16], 1u);
    }
    __syncthreads();

    // stage 1 selection: wave wv handles order-stat wv
    {
        float nf = (float)n;
        float m1 = fmaxf(nf - 1.0f, 0.0f);
        float pos = ((wv >> 1) ? 0.75f : 0.25f) * m1;   // exact in f32
        unsigned k = (unsigned)((wv & 1) ? (int)ceilf(pos) : (int)floorf(pos));
        unsigned bucket, krem;
        sel256(s_h1, k, lane, bucket, krem);
        if (lane == 0) { s_pref[wv] = bucket; s_krem[wv] = krem; }
    }
    __syncthreads();

    // stage 2: bits[15:8]
    {
        unsigned p0 = s_pref[0], p1 = s_pref[1], p2 = s_pref[2], p3 = s_pref[3];
        for (int j = tid; j < n; j += 256) {
            unsigned v = s_key[j];
            unsigned t8 = v >> 16, b8 = (v >> 8) & 255u;
            if (t8 == p0) atomicAdd(&s_h2[b8], 1u);
            if (t8 == p1) atomicAdd(&s_h2[256 + b8], 1u);
            if (t8 == p2) atomicAdd(&s_h2[512 + b8], 1u);
            if (t8 == p3) atomicAdd(&s_h2[768 + b8], 1u);
        }
    }
    __syncthreads();
    {
        unsigned bucket, krem;
        sel256(&s_h2[wv * 256], s_krem[wv], lane, bucket, krem);
        if (lane == 0) { s_pref[wv] = (s_pref[wv] << 8) | bucket; s_krem[wv] = krem; }
    }
    __syncthreads();
    #pragma unroll
    for (int j = 0; j < 4; ++j) s_h2[j * 256 + tid] = 0u;
    __syncthreads();

    // stage 3: bits[7:0]
    {
        unsigned p0 = s_pref[0], p1 = s_pref[1], p2 = s_pref[2], p3 = s_pref[3];
        for (int j = tid; j < n; j += 256) {
            unsigned v = s_key[j];
            unsigned t16 = v >> 8, b8 = v & 255u;
            if (t16 == p0) atomicAdd(&s_h2[b8], 1u);
            if (t16 == p1) atomicAdd(&s_h2[256 + b8], 1u);
            if (t16 == p2) atomicAdd(&s_h2[512 + b8], 1u);
            if (t16 == p3) atomicAdd(&s_h2[768 + b8], 1u);
        }
    }
    __syncthreads();
    {
        unsigned bucket, krem;
        sel256(&s_h2[wv * 256], s_krem[wv], lane, bucket, krem);
        if (lane == 0) s_val[wv] = __uint_as_float(BASE_BITS + ((s_pref[wv] << 8) | bucket));
    }
    __syncthreads();

    if (tid == 0) {
        // mirror reference f32 arithmetic with non-fused IEEE ops (verified absmax 0.0)
        float nf = (float)n;
        float m1 = fmaxf(nf - 1.0f, 0.0f);
        float pos1 = 0.25f * m1, pos3 = 0.75f * m1;
        float fr1 = pos1 - floorf(pos1);
        float fr3 = pos3 - floorf(pos3);
        float q1 = __fadd_rn(__fmul_rn(s_val[0], __fsub_rn(1.0f, fr1)),
                             __fmul_rn(s_val[1], fr1));
        float q3 = __fadd_rn(__fmul_rn(s_val[2], __fsub_rn(1.0f, fr3)),
                             __fmul_rn(s_val[3], fr3));
        float iqr = __fsub_rn(q3, q1);
        float t15 = __fmul_rn(1.5f, iqr);
        s_lb = __fsub_rn(q1, t15);
        s_ub = __fadd_rn(q3, t15);
    }
    __syncthreads();

    // stable compaction straight from the LDS lists (order = pixel order)
    const float lb = s_lb, ub = s_ub;
    for (int c0 = 0; c0 < n; c0 += 256) {
        int j = c0 + tid;
        bool pass = false;
        float d = 0.0f;
        unsigned idx = 0;
        if (j < n) {
            idx = s_idx[j];
            d = __uint_as_float(s_key[j] + BASE_BITS);
            pass = (d >= lb) && (d <= ub);
        }
        unsigned c = pass ? 1u : 0u;
        unsigned incl = wave_incl_scan_u32(c, lane);
        if (lane == 63) s_wc[wv] = incl;
        __syncthreads();                               // B1
        if (tid == 0) {
            unsigned o = s_gbase;
            #pragma unroll
            for (int w = 0; w < 4; ++w) { s_wo[w] = o; o += s_wc[w]; }
            s_gbase = o;
        }
        __syncthreads();                               // B2
        if (pass) {
            unsigned o = s_wo[wv] + (incl - c);
            if (o < CAP) {
                int y = (int)idx / W_IMG, x = (int)idx - y * W_IMG;
                r0[o]            = __fmul_rn(s_xc[x], d);
                r0[cstr + o]     = __fmul_rn(s_yc[y], d);
                r0[2 * cstr + o] = d;
            }
        }
        if (s_gbase >= (unsigned)CAP) break;           // uniform; count can only grow
    }
    __syncthreads();
    unsigned cntv = s_gbase;
    unsigned cl = cntv > (unsigned)CAP ? (unsigned)CAP : cntv;
    for (int j = (int)cl + tid; j < CAP; j += 256) {
        r0[j] = 0.0f; r0[cstr + j] = 0.0f; r0[2 * cstr + j] = 0.0f;
    }
    if (tid == 0) {
        r0[CAP] = (cntv > 0u) ? 1.0f : 0.0f;           // n>0 => >=1 passes (q-stat element)
        r0[cstr + CAP] = 0.0f;
        r0[2 * cstr + CAP] = 0.0f;
    }
}

// ================= Fallback: verified round-4 single kernel =================
#define NTHR 1024
#define NWAVE 16
#define CAPS 384
#define NREG (NWAVE * NPERS)

__device__ __forceinline__ void find_bucket_fb(const unsigned* h, int nchunks, unsigned k,
                                               int lane, unsigned& bucket, unsigned& cl) {
    unsigned run = 0;
    bucket = 0; cl = 0;
    bool found = false;
    for (int c = 0; c < nchunks; ++c) {
        if (found) break;
        unsigned hv = h[c * 64 + lane] & 0xFFFFu;
        unsigned inc = wave_incl_scan_u32(hv, lane);
        unsigned tot = __shfl(inc, 63, 64);
        if (run + tot > k) {
            unsigned long long m = __ballot((run + inc) > k);
            int l = (int)__builtin_ctzll(m);
            bucket = (unsigned)(c * 64 + l);
            cl = run + __shfl(inc, l, 64) - __shfl(hv, l, 64);
            found = true;
        }
        run += tot;
    }
}

__global__ __launch_bounds__(NTHR)
void fb_kernel(const float* __restrict__ in, float* __restrict__ out) {
    const int b = blockIdx.x;
    const int tid = (int)threadIdx.x;
    const int lane = tid & 63;
    const int wv = tid >> 6;
    const float* __restrict__ depth = in + (size_t)b * 3u * HW_N;
    const float* __restrict__ indc = depth + HW_N;
    const float4* __restrict__ d4p = (const float4*)depth;
    const float4* __restrict__ i4p = (const float4*)indc;

    __shared__ unsigned s_vals[NREG * CAPS];
    __shared__ unsigned s_cur[NREG];
    __shared__ unsigned s_h1[NPERS * 256];
    __shared__ unsigned s_h2[20 * 256];
    __shared__ __align__(16) unsigned s_pref[24];
    __shared__ int      s_krem[20];
    __shared__ float    s_val[20];
    __shared__ unsigned s_n[NPERS];
    __shared__ float    s_lb[NPERS], s_ub[NPERS];
    __shared__ unsigned s_cnt[NWAVE][NPERS];
    __shared__ unsigned s_woff[NWAVE][NPERS];
    __shared__ unsigned s_tot[NPERS];
    __shared__ unsigned s_base[NPERS];
    __shared__ float    s_xc[W_IMG];
    __shared__ float    s_yc[H_IMG];

    for (int i = tid; i < NPERS * 256; i += NTHR) s_h1[i] = 0u;
    for (int i = tid; i < 20 * 256; i += NTHR) s_h2[i] = 0u;
    if (tid < NREG) s_cur[tid] = 0u;
    if (tid < NPERS) { s_base[tid] = 0u; s_tot[tid] = 0u; }
    if (tid < W_IMG) {
        const double fx = 200.0 / (2.0 * tan((81.0 * (M_PI / 180.0)) / 2.0));
        s_xc[tid] = (float)(((double)tid - 100.0) / fx);
    }
    {
        int ty = tid - 256;
        if (ty >= 0 && ty < H_IMG) {
            const double fy = 150.0 / (2.0 * tan((59.0 * (M_PI / 180.0)) / 2.0));
            s_yc[ty] = (float)(((double)ty - 75.0) / fy);
        }
    }
    __syncthreads();

    {
        int i = tid;
        float4 dd = d4p[i], ff = i4p[i];
        while (i < NV4) {
            int inx = i + NTHR;
            float4 dd2, ff2;
            if (inx < NV4) { dd2 = d4p[inx]; ff2 = i4p[inx]; }
            float de[4] = {dd.x, dd.y, dd.z, dd.w};
            float fe[4] = {ff.x, ff.y, ff.z, ff.w};
            #pragma unroll
            for (int e = 0; e < 4; ++e) {
                float d = de[e];
                int p = person_of(fe[e]);
                if (p && d > 3.0f) {
                    unsigned k24 = __float_as_uint(d) - BASE_BITS;
                    atomicAdd(&s_h1[(p - 1) * 256 + (k24 >> 16)], 1u);
                    int reg = wv * NPERS + (p - 1);
                    unsigned off = atomicAdd(&s_cur[reg], 1u);
                    if (off < CAPS) s_vals[reg * CAPS + off] = k24;
                }
            }
            dd = dd2; ff = ff2;
            i = inx;
        }
    }
    __syncthreads();

    if (tid < NPERS) {
        unsigned n = 0;
        for (int sh = 0; sh < NWAVE; ++sh) n += s_cur[sh * NPERS + tid];
        s_n[tid] = n;
    }
    __syncthreads();

    for (int q = wv; q < 20; q += NWAVE) {
        int p = q >> 2, s = q & 3;
        unsigned n = s_n[p];
        if (n == 0u) { if (lane == 0) s_pref[q] = 0xFFFFFFFFu; continue; }
        float nf = (float)n;
        float m1 = fmaxf(nf - 1.0f, 0.0f);
        float pos = ((s >> 1) ? 0.75f : 0.25f) * m1;
        unsigned k = (unsigned)((s & 1) ? (int)ceilf(pos) : (int)floorf(pos));
        unsigned bucket, cl;
        find_bucket_fb(&s_h1[p * 256], 4, k, lane, bucket, cl);
        if (lane == 0) { s_pref[q] = bucket; s_krem[q] = (int)(k - cl); }
    }
    __syncthreads();

    for (int t = tid; t < NREG * CAPS; t += NTHR) {
        int reg = t / CAPS;
        int ii = t - reg * CAPS;
        unsigned cnt = s_cur[reg]; if (cnt > CAPS) cnt = CAPS;
        if ((unsigned)ii < cnt) {
            unsigned k24 = s_vals[t];
            int p = reg % NPERS;
            unsigned t8 = k24 >> 16;
            uint4 pr = *(const uint4*)&s_pref[p * 4];
            unsigned b8 = (k24 >> 8) & 255u;
            if (t8 == pr.x) atomicAdd(&s_h2[(p * 4 + 0) * 256 + b8], 1u);
            if (t8 == pr.y) atomicAdd(&s_h2[(p * 4 + 1) * 256 + b8], 1u);
            if (t8 == pr.z) atomicAdd(&s_h2[(p * 4 + 2) * 256 + b8], 1u);
            if (t8 == pr.w) atomicAdd(&s_h2[(p * 4 + 3) * 256 + b8], 1u);
        }
    }
    __syncthreads();

    for (int q = wv; q < 20; q += NWAVE) {
        int p = q >> 2;
        if (s_n[p] == 0u) continue;
        unsigned bucket, cl;
        find_bucket_fb(&s_h2[q * 256], 4, (unsigned)s_krem[q], lane, bucket, cl);
        if (lane == 0) { s_pref[q] = (s_pref[q] << 8) | bucket; s_krem[q] -= (int)cl; }
    }
    __syncthreads();
    for (int i = tid; i < 20 * 256; i += NTHR) s_h2[i] = 0u;
    __syncthreads();

    for (int t = tid; t < NREG * CAPS; t += NTHR) {
        int reg = t / CAPS;
        int ii = t - reg * CAPS;
        unsigned cnt = s_cur[reg]; if (cnt > CAPS) cnt = CAPS;
        if ((unsigned)ii < cnt) {
            unsigned k24 = s_vals[t];
            int p = reg % NPERS;
            unsigned t16 = k24 >> 8;
            uint4 pr = *(const uint4*)&s_pref[p * 4];
            unsigned b8 = k24 & 255u;
            if (t16 == pr.x) atomicAdd(&s_h2[(p * 4 + 0) * 256 + b8], 1u);
            if (t16 == pr.y) atomicAdd(&s_h2[(p * 4 + 1) * 256 + b8], 1u);
            if (t16 == pr.z) atomicAdd(&s_h2[(p * 4 + 2) * 256 + b8], 1u);
            if (t16 == pr.w) atomicAdd(&s_h2[(p * 4 + 3) * 256 + b8], 1u);
        }
    }
    __syncthreads();

    for (int q = wv; q < 20; q += NWAVE) {
        int p = q >> 2;
        if (s_n[p] == 0u) continue;
        unsigned bucket, cl;
        find_bucket_fb(&s_h2[q * 256], 4, (unsigned)s_krem[q], lane, bucket, cl);
        if (lane == 0) s_val[q] = __uint_as_float(BASE_BITS + ((s_pref[q] << 8) | bucket));
    }
    __syncthreads();

    if (tid < NPERS) {
        if (s_n[tid] == 0u) {
            s_lb[tid] = INFINITY; s_ub[tid] = -INFINITY;
        } else {
            float nf = (float)s_n[tid];
            float m1 = fmaxf(nf - 1.0f, 0.0f);
            float pos1 = 0.25f * m1, pos3 = 0.75f * m1;
            float fr1 = pos1 - floorf(pos1);
            float fr3 = pos3 - floorf(pos3);
            float q1 = __fadd_rn(__fmul_rn(s_val[tid * 4 + 0], __fsub_rn(1.0f, fr1)),
                                 __fmul_rn(s_val[tid * 4 + 1], fr1));
            float q3 = __fadd_rn(__fmul_rn(s_val[tid * 4 + 2], __fsub_rn(1.0f, fr3)),
                                 __fmul_rn(s_val[tid * 4 + 3], fr3));
            float iqr = __fsub_rn(q3, q1);
            float t15 = __fmul_rn(1.5f, iqr);
            s_lb[tid] = __fsub_rn(q1, t15);
            s_ub[tid] = __fadd_rn(q3, t15);
        }
    }
    __syncthreads();

    float* outb = out + (size_t)b * 3u * (NPERS * (CAP + 1));
    const int cstr = NPERS * (CAP + 1);

    for (int t0 = 0; t0 < NV4; t0 += NTHR) {
        int i = t0 + tid;
        int pf[4] = {0, 0, 0, 0};
        float dv[4] = {0.f, 0.f, 0.f, 0.f};
        if (i < NV4) {
            float4 dd = d4p[i];
            float4 ff = i4p[i];
            float de[4] = {dd.x, dd.y, dd.z, dd.w};
            float fe[4] = {ff.x, ff.y, ff.z, ff.w};
            #pragma unroll
            for (int e = 0; e < 4; ++e) {
                float d = de[e];
                int p = person_of(fe[e]);
                dv[e] = d;
                if (p && d > 3.0f && d >= s_lb[p - 1] && d <= s_ub[p - 1]) pf[e] = p;
            }
        }
        unsigned wexc[NPERS];
        #pragma unroll
        for (int pp = 0; pp < NPERS; ++pp) {
            unsigned c = (unsigned)((pf[0] == pp + 1) + (pf[1] == pp + 1) +
                                    (pf[2] == pp + 1) + (pf[3] == pp + 1));
            unsigned incl = wave_incl_scan_u32(c, lane);
            if (lane == 63) s_cnt[wv][pp] = incl;
            wexc[pp] = incl - c;
        }
        __syncthreads();
        if (tid < 16 * NPERS) {
            int p = tid >> 4, w = tid & 15;
            unsigned o = s_base[p];
            for (int w2 = 0; w2 < w; ++w2) o += s_cnt[w2][p];
            s_woff[w][p] = o;
            if (w == 15) s_tot[p] = o + s_cnt[15][p];
        }
        __syncthreads();
        #pragma unroll
        for (int pp = 0; pp < NPERS; ++pp) {
            unsigned m0 = (pf[0] == pp + 1), m1 = (pf[1] == pp + 1);
            unsigned m2 = (pf[2] == pp + 1), m3 = (pf[3] == pp + 1);
            if ((m0 | m1 | m2 | m3) != 0u) {
                unsigned basep = s_woff[wv][pp] + wexc[pp];
                #define WRITEPT(e, mm, pre)                                                \
                    if (mm) { unsigned off = basep + (pre);                                \
                        if (off < CAP) {                                                   \
                            int idx = i * 4 + e; int y = idx / W_IMG; int x = idx - y * W_IMG; \
                            size_t o = (size_t)pp * (CAP + 1) + off; float d = dv[e];      \
                            outb[o] = __fmul_rn(s_xc[x], d);                               \
                            outb[cstr + o] = __fmul_rn(s_yc[y], d);                        \
                            outb[2 * cstr + o] = d; } }
                WRITEPT(0, m0, 0u)
                WRITEPT(1, m1, m0)
                WRITEPT(2, m2, m0 + m1)
                WRITEPT(3, m3, m0 + m1 + m2)
                #undef WRITEPT
            }
        }
        if (tid < NPERS) s_base[tid] = s_tot[tid];
        bool done = true;
        #pragma unroll
        for (int pp = 0; pp < NPERS; ++pp) done = done && (s_tot[pp] >= (unsigned)CAP);
        if (done) break;
    }
    __syncthreads();

    for (int t = tid; t < NPERS * (CAP + 1); t += NTHR) {
        int p = t / (CAP + 1);
        int j = t - p * (CAP + 1);
        unsigned cnt = s_tot[p];
        size_t o = (size_t)p * (CAP + 1) + j;
        if (j == CAP) {
            outb[o] = (cnt > 0u) ? 1.0f : 0.0f;
            outb[cstr + o] = 0.0f;
            outb[2 * cstr + o] = 0.0f;
        } else if ((unsigned)j >= cnt) {
            outb[o] = 0.0f;
            outb[cstr + o] = 0.0f;
            outb[2 * cstr + o] = 0.0f;
        }
    }
}

extern "C" void kernel_launch(void* const* d_in, const int* in_sizes, int n_in,
                              void* d_out, int out_size, void* d_ws, size_t ws_size,
                              hipStream_t stream) {
    const float* in = (const float*)d_in[0];
    float* out = (float*)d_out;
    int B = in_sizes[0] / (3 * HW_N);   // 256

    const size_t vals_bytes = (size_t)B * NPERS * NSUB * REG * sizeof(unsigned short); // 11.8 MB
    const size_t cnt_bytes  = (size_t)B * NPERS * NSUB * sizeof(unsigned);             // 20 KB
    const size_t req        = vals_bytes + cnt_bytes;

    if (ws_size >= req) {
        unsigned short* vals16 = (unsigned short*)d_ws;
        unsigned* cnt4 = (unsigned*)((char*)d_ws + vals_bytes);
        hipLaunchKernelGGL(k1_capture, dim3(B * NSUB), dim3(256), 0, stream, in, vals16, cnt4);
        hipLaunchKernelGGL(k2_out, dim3(B * NPERS), dim3(256), 0, stream, in, vals16, cnt4, out);
    } else {
        hipLaunchKernelGGL(fb_kernel, dim3(B), dim3(NTHR), 0, stream, in, out);
    }
}